// Round 13
// baseline (195.429 us; speedup 1.0000x reference)
//
#include <hip/hip_runtime.h>
#include <cmath>

// SSIM + L1 image similarity loss, MI355X (gfx950).
// es, ta: fp32 [16,3,512,512]. Output: out[0]=l1_loss, out[1]=ssim_loss.
//
// R13: R12 was clean (no spill, 67% VALUBusy) but structurally pays 2.25x
// h-conv redundancy + LDS staging round-trip + barriers. New shape:
// column-walking waves, no LDS at all.
//  - wave = 64-col strip x 32-row band; lane walks its column downward.
//  - 11-slot circular register window of horizontal sums; trip loop of
//    11-unrolled rows makes j%11==i STATIC (R7's scratch trap avoided
//    without 42x code bloat).
//  - taps read straight from global: 11 coalesced 256B loads per row per
//    input; neighboring taps/rows hit L1/L2 (row of 2KB; 11x reuse).
//  - readfirstlane(wv) -> row base stays SGPR -> loads are
//    global_load_dword v,[co4],s[base] with ZERO per-row address VALU.
//  - image edges: per-lane premasked weights gw[k] (0 outside) + clamped
//    column offsets -> no per-tap branches, exact zero-pad semantics.
//  - redundancy 42/32 = 1.31x (vs 2.25x). No barriers, no staging.
// launch_bounds(256,2) = proven VGPR cap 128; est live ~110.

constexpr int IMG = 512;
constexpr int WIN = 11;
constexpr int RPB = 32;                 // output rows per wave (band)
constexpr int STREAM = RPB + WIN - 1;   // 42 streamed rows
constexpr float C1C = 0.01f * 0.01f;
constexpr float C2C = 0.03f * 0.03f;

struct Wnd { float g[WIN]; };

__global__ __launch_bounds__(256, 2) void ssim_main(
    const float* __restrict__ es, const float* __restrict__ ta,
    float2* __restrict__ partials, Wnd w)
{
    const int tid = threadIdx.x;
    const int wv = __builtin_amdgcn_readfirstlane(tid >> 6);  // scalar wave id
    const int ln = tid & 63;
    const int band = blockIdx.y * 4 + wv;      // 0..15
    const int r0 = band * RPB;
    const int c  = blockIdx.x * 64 + ln;       // global column
    const int img = blockIdx.z;
    const float* pe = es + (size_t)img * (IMG * IMG);
    const float* pt = ta + (size_t)img * (IMG * IMG);

    // per-lane masked weights + clamped column offsets (edge zero-pad)
    float gw[WIN];
    int   co[WIN];
    #pragma unroll
    for (int k = 0; k < WIN; ++k) {
        int cc = c - 5 + k;
        bool v = (cc >= 0) && (cc < IMG);
        co[k] = cc < 0 ? 0 : (cc >= IMG ? IMG - 1 : cc);
        gw[k] = v ? w.g[k] : 0.f;
    }

    // circular window of horizontal sums (5 quantities x 11 slots)
    float w0[WIN], w1[WIN], w2[WIN], w3[WIN], w4[WIN];
    float ssim_s = 0.f, l1_s = 0.f;

    for (int t = 0; t < 4; ++t) {              // rolled: 4 trips
        #pragma unroll
        for (int i = 0; i < WIN; ++i) {        // static i -> static slots
            const int j = t * WIN + i;         // j % 11 == i
            if (j >= STREAM) break;            // tail guard (t==3, i>=9)
            const int gi = r0 - 5 + j;         // global input row

            float hm1 = 0.f, hm2 = 0.f, h11 = 0.f, h22 = 0.f, h12 = 0.f;
            if (gi >= 0 && gi < IMG) {         // wave-uniform row validity
                const float* re = pe + gi * IMG;   // SGPR base
                const float* rt = pt + gi * IMG;
                float e5 = 0.f, t5 = 0.f;
                #pragma unroll
                for (int k = 0; k < WIN; ++k) {
                    float e  = re[co[k]];
                    float tt = rt[co[k]];
                    if (k == 5) { e5 = e; t5 = tt; }
                    float gk = gw[k];
                    float ge = gk * e;
                    float gt = gk * tt;
                    hm1 += ge;  hm2 += gt;
                    h11 += ge * e;  h22 += gt * tt;  h12 += ge * tt;
                }
                if (j >= 5 && j < 5 + RPB)     // center row of an owned output
                    l1_s += fabsf(e5 - t5);
            }
            w0[i] = hm1; w1[i] = hm2; w2[i] = h11; w3[i] = h22; w4[i] = h12;

            if (j >= WIN - 1) {                // emit output row r0 + (j-10)
                float mu1 = 0.f, mu2 = 0.f, x11 = 0.f, x22 = 0.f, x12 = 0.f;
                #pragma unroll
                for (int k = 0; k < WIN; ++k) {
                    const int s = (i + 1 + k) % WIN;   // static slot
                    float gk = w.g[k];
                    mu1 += gk * w0[s];
                    mu2 += gk * w1[s];
                    x11 += gk * w2[s];
                    x22 += gk * w3[s];
                    x12 += gk * w4[s];
                }
                float m11 = mu1 * mu1, m22 = mu2 * mu2, m12 = mu1 * mu2;
                float s11 = x11 - m11, s22 = x22 - m22, s12 = x12 - m12;
                float num = (2.f * m12 + C1C) * (2.f * s12 + C2C);
                float den = (m11 + m22 + C1C) * (s11 + s22 + C2C);
                ssim_s += num * __builtin_amdgcn_rcpf(den);
            }
        }
    }

    // ---- wave reduce + one partial store per wave ----
    #pragma unroll
    for (int off = 32; off >= 1; off >>= 1) {
        ssim_s += __shfl_xor(ssim_s, off, 64);
        l1_s   += __shfl_xor(l1_s, off, 64);
    }
    if (ln == 0) {
        int widx = ((img * (int)gridDim.y + blockIdx.y) * (int)gridDim.x
                    + blockIdx.x) * 4 + wv;
        partials[widx] = make_float2(ssim_s, l1_s);
    }
}

__global__ __launch_bounds__(256) void ssim_reduce(
    const float2* __restrict__ partials, int n, float* __restrict__ out)
{
    __shared__ float2 red[4];
    const int tid = threadIdx.x;
    float ssim_s = 0.f, l1_s = 0.f;
    for (int i = tid; i < n; i += 256) {
        float2 p = partials[i];
        ssim_s += p.x;
        l1_s   += p.y;
    }
    #pragma unroll
    for (int off = 32; off >= 1; off >>= 1) {
        ssim_s += __shfl_xor(ssim_s, off, 64);
        l1_s   += __shfl_xor(l1_s, off, 64);
    }
    if ((tid & 63) == 0) red[tid >> 6] = make_float2(ssim_s, l1_s);
    __syncthreads();
    if (tid == 0) {
        float s = red[0].x + red[1].x + red[2].x + red[3].x;
        float l = red[0].y + red[1].y + red[2].y + red[3].y;
        const float N = 16.f * 3.f * 512.f * 512.f;
        out[0] = 0.15f * (l / N);
        out[1] = 0.85f * 0.5f * (1.f - s / N);
    }
}

extern "C" void kernel_launch(void* const* d_in, const int* in_sizes, int n_in,
                              void* d_out, int out_size, void* d_ws, size_t ws_size,
                              hipStream_t stream)
{
    const float* es = (const float*)d_in[0];
    const float* ta = (const float*)d_in[1];
    float* out = (float*)d_out;
    float2* partials = (float2*)d_ws;

    Wnd w;
    double gd[WIN], sum = 0.0;
    for (int i = 0; i < WIN; ++i) {
        double x = (double)(i - WIN / 2);
        gd[i] = std::exp(-(x * x) / (2.0 * 1.5 * 1.5));
        sum += gd[i];
    }
    for (int i = 0; i < WIN; ++i) w.g[i] = (float)(gd[i] / sum);

    const int nimg = in_sizes[0] / (IMG * IMG);      // 48
    dim3 grid(IMG / 64, (IMG / RPB) / 4, nimg);      // 8 x 4 x 48 blocks
    const int nwaves = grid.x * grid.y * grid.z * 4; // 6144 wave partials
    ssim_main<<<grid, 256, 0, stream>>>(es, ta, partials, w);
    ssim_reduce<<<1, 256, 0, stream>>>(partials, nwaves, out);
}

// Round 14
// 135.333 us; speedup vs baseline: 1.4441x; 1.4441x over previous
//
#include <hip/hip_runtime.h>
#include <cmath>

// SSIM + L1 image similarity loss, MI355X (gfx950).
// es, ta: fp32 [16,3,512,512]. Output: out[0]=l1_loss, out[1]=ssim_loss.
//
// R14 = R12 (proven: no spill, VGPR 128, 152us) with the (e,t)-symmetric
// inner math rewritten as ext_vector_type(2) float pairs so the backend
// can select v_pk_{mul,add,fma}_f32 (VOP3P packed fp32, gfx90a+):
//   per tap:   7 scalar VALU -> ~4 (pk_mul + pk_add + pk_fma + fma)
//   scatter:   5 FMA -> 3 (2 pk_fma + fma)
// Structure, tile (64x32), LDS (float2-interleaved, 25.5KB), cap (256,2),
// partial-store tail: identical to R12. One variable.

typedef float v2f __attribute__((ext_vector_type(2)));

constexpr int TILE_W = 64;
constexpr int TILE_H = 32;
constexpr int HALO = 5;
constexpr int WIN  = 11;
constexpr int ROWS_PER_WAVE = TILE_H / 4;            // 8
constexpr int STREAM_ROWS = ROWS_PER_WAVE + WIN - 1; // 18
constexpr int LH   = TILE_H + 2 * HALO;  // 42 staged rows
constexpr int LW   = TILE_W + 2 * HALO;  // 74 staged cols
constexpr int LSTR = 76;                 // LDS row stride (float2 units)
constexpr int IMG  = 512;
constexpr float C1C = 0.01f * 0.01f;
constexpr float C2C = 0.03f * 0.03f;

struct Wnd { float g[WIN]; };

__global__ __launch_bounds__(256, 2) void ssim_main(
    const float* __restrict__ es, const float* __restrict__ ta,
    float2* __restrict__ partials, Wnd w)
{
    __shared__ v2f sS[LH * LSTR];
    __shared__ float2 red[4];

    const int tid = threadIdx.x;
    const int tx0 = blockIdx.x * TILE_W;
    const int ty0 = blockIdx.y * TILE_H;
    const int img = blockIdx.z;
    const float* pe = es + (size_t)img * (IMG * IMG);
    const float* pt = ta + (size_t)img * (IMG * IMG);

    // ---- stage interleaved {e,t} tile (zero-pad outside image) ----
    for (int i = tid; i < LH * LW; i += 256) {
        int r = i / LW;
        int c = i - r * LW;
        int gy = ty0 - HALO + r;
        int gx = tx0 - HALO + c;
        v2f v = {0.f, 0.f};
        if (gy >= 0 && gy < IMG && gx >= 0 && gx < IMG) {
            int off = gy * IMG + gx;
            v.x = pe[off];
            v.y = pt[off];
        }
        sS[r * LSTR + c] = v;
    }
    __syncthreads();

    const int wv = tid >> 6;   // wave id 0..3 -> 8-row segment
    const int ln = tid & 63;   // lane -> column
    const int rbase = wv * ROWS_PER_WAVE;
    const v2f* rp = &sS[rbase * LSTR + ln];

    v2f am[ROWS_PER_WAVE];     // (mu1, mu2) accumulators
    v2f aq[ROWS_PER_WAVE];     // (E[e^2], E[t^2]) accumulators
    float ax[ROWS_PER_WAVE];   // E[e*t] accumulator
    #pragma unroll
    for (int o = 0; o < ROWS_PER_WAVE; ++o) {
        am[o] = (v2f){0.f, 0.f}; aq[o] = (v2f){0.f, 0.f}; ax[o] = 0.f;
    }

    #pragma unroll
    for (int rr = 0; rr < STREAM_ROWS; ++rr) {
        // horizontal 11-tap of {(e,t), (e^2,t^2), e*t} for streamed row rr
        v2f hm = {0.f, 0.f};
        v2f hq = {0.f, 0.f};
        float hx = 0.f;
        #pragma unroll
        for (int k = 0; k < WIN; ++k) {
            v2f et = rp[rr * LSTR + k];     // ds_read_b64, imm offset
            float gk = w.g[k];
            v2f g2 = {gk, gk};
            v2f ge = g2 * et;               // v_pk_mul_f32
            hm += ge;                       // v_pk_add_f32
            hq += ge * et;                  // v_pk_fma_f32
            hx += ge.x * et.y;              // scalar v_fmac_f32
        }

        // vertical scatter: streamed row rr feeds output rows rr-10..rr
        #pragma unroll
        for (int k = 0; k < WIN; ++k) {
            int o = rr - k;
            if (o >= 0 && o < ROWS_PER_WAVE) {
                float gk = w.g[k];
                v2f g2 = {gk, gk};
                am[o] += g2 * hm;           // v_pk_fma_f32
                aq[o] += g2 * hq;           // v_pk_fma_f32
                ax[o] += gk * hx;           // v_fmac_f32
            }
        }
    }

    // ---- epilogue: ssim per pixel + L1, then reduce ----
    float ssim_s = 0.f, l1_s = 0.f;
    #pragma unroll
    for (int o = 0; o < ROWS_PER_WAVE; ++o) {
        float mu1 = am[o].x, mu2 = am[o].y;
        float m11 = mu1 * mu1, m22 = mu2 * mu2, m12 = mu1 * mu2;
        float s11 = aq[o].x - m11;
        float s22 = aq[o].y - m22;
        float s12 = ax[o]   - m12;
        float num = (2.f * m12 + C1C) * (2.f * s12 + C2C);
        float den = (m11 + m22 + C1C) * (s11 + s22 + C2C);
        ssim_s += num * __builtin_amdgcn_rcpf(den);

        v2f c = rp[(o + HALO) * LSTR + HALO];  // center {e,t}
        l1_s += fabsf(c.x - c.y);
    }

    // ---- block reduce: wave shfl -> LDS[4] -> thread 0 stores partial ----
    #pragma unroll
    for (int off = 32; off >= 1; off >>= 1) {
        ssim_s += __shfl_xor(ssim_s, off, 64);
        l1_s   += __shfl_xor(l1_s, off, 64);
    }
    if (ln == 0) red[wv] = make_float2(ssim_s, l1_s);
    __syncthreads();
    if (tid == 0) {
        float2 r0 = red[0], r1 = red[1], r2 = red[2], r3 = red[3];
        float2 p = make_float2(r0.x + r1.x + r2.x + r3.x,
                               r0.y + r1.y + r2.y + r3.y);
        int bid = (blockIdx.z * gridDim.y + blockIdx.y) * gridDim.x + blockIdx.x;
        partials[bid] = p;
    }
}

__global__ __launch_bounds__(256) void ssim_reduce(
    const float2* __restrict__ partials, int n, float* __restrict__ out)
{
    __shared__ float2 red[4];
    const int tid = threadIdx.x;
    float ssim_s = 0.f, l1_s = 0.f;
    for (int i = tid; i < n; i += 256) {
        float2 p = partials[i];
        ssim_s += p.x;
        l1_s   += p.y;
    }
    #pragma unroll
    for (int off = 32; off >= 1; off >>= 1) {
        ssim_s += __shfl_xor(ssim_s, off, 64);
        l1_s   += __shfl_xor(l1_s, off, 64);
    }
    if ((tid & 63) == 0) red[tid >> 6] = make_float2(ssim_s, l1_s);
    __syncthreads();
    if (tid == 0) {
        float s = red[0].x + red[1].x + red[2].x + red[3].x;
        float l = red[0].y + red[1].y + red[2].y + red[3].y;
        const float N = 16.f * 3.f * 512.f * 512.f;
        out[0] = 0.15f * (l / N);
        out[1] = 0.85f * 0.5f * (1.f - s / N);
    }
}

extern "C" void kernel_launch(void* const* d_in, const int* in_sizes, int n_in,
                              void* d_out, int out_size, void* d_ws, size_t ws_size,
                              hipStream_t stream)
{
    const float* es = (const float*)d_in[0];
    const float* ta = (const float*)d_in[1];
    float* out = (float*)d_out;
    float2* partials = (float2*)d_ws;

    Wnd w;
    double gd[WIN], sum = 0.0;
    for (int i = 0; i < WIN; ++i) {
        double x = (double)(i - WIN / 2);
        gd[i] = std::exp(-(x * x) / (2.0 * 1.5 * 1.5));
        sum += gd[i];
    }
    for (int i = 0; i < WIN; ++i) w.g[i] = (float)(gd[i] / sum);

    const int nimg = in_sizes[0] / (IMG * IMG);  // 16*3 = 48
    dim3 grid(IMG / TILE_W, IMG / TILE_H, nimg); // 8 x 16 x 48 = 6144 blocks
    const int nblocks = grid.x * grid.y * grid.z;
    ssim_main<<<grid, 256, 0, stream>>>(es, ta, partials, w);
    ssim_reduce<<<1, 256, 0, stream>>>(partials, nblocks, out);
}

// Round 15
// 109.309 us; speedup vs baseline: 1.7879x; 1.2381x over previous
//
#include <hip/hip_runtime.h>
#include <cmath>

// SSIM + L1 image similarity loss, MI355X (gfx950).
// es, ta: fp32 [16,3,512,512]. Output: out[0]=l1_loss, out[1]=ssim_loss.
//
// R15 = R14 (135us: packed v2f math, 64x32 tile, VGPR=128 no-spill) with
// ONE change: branch-free BATCHED staging.
// Diagnosis: R12->R14 idle time rose (50->66us) while VALU busy fell --
// latency-bound critical path. The stage loop's bounds-branch wrapped the
// loads (load inside `if`), blocking cross-iteration hoisting -> ~12
// serialized HBM round-trips per block before the barrier; only 4 resident
// blocks/CU to cover it. Fix (G15 async-STAGE):
//   loop1: issue ALL 26 loads at CLAMPED (always-valid) addresses into
//          static-indexed register arrays -- no branches around loads;
//   loop2: single wait, ds_write with zero-pad applied as multiply-mask.
// ~12 round trips -> ~1. Main loop / tile / cap / tail identical to R14.

typedef float v2f __attribute__((ext_vector_type(2)));

constexpr int TILE_W = 64;
constexpr int TILE_H = 32;
constexpr int HALO = 5;
constexpr int WIN  = 11;
constexpr int ROWS_PER_WAVE = TILE_H / 4;            // 8
constexpr int STREAM_ROWS = ROWS_PER_WAVE + WIN - 1; // 18
constexpr int LH   = TILE_H + 2 * HALO;  // 42 staged rows
constexpr int LW   = TILE_W + 2 * HALO;  // 74 staged cols
constexpr int LSTR = 76;                 // LDS row stride (v2f units)
constexpr int IMG  = 512;
constexpr int TOTAL = LH * LW;           // 3108 staged elements
constexpr int NIT = (TOTAL + 255) / 256; // 13 stage iterations
constexpr float C1C = 0.01f * 0.01f;
constexpr float C2C = 0.03f * 0.03f;

struct Wnd { float g[WIN]; };

__global__ __launch_bounds__(256, 2) void ssim_main(
    const float* __restrict__ es, const float* __restrict__ ta,
    float2* __restrict__ partials, Wnd w)
{
    __shared__ v2f sS[LH * LSTR];
    __shared__ float2 red[4];

    const int tid = threadIdx.x;
    const int tx0 = blockIdx.x * TILE_W;
    const int ty0 = blockIdx.y * TILE_H;
    const int img = blockIdx.z;
    const float* pe = es + (size_t)img * (IMG * IMG);
    const float* pt = ta + (size_t)img * (IMG * IMG);

    // ---- stage, phase A: issue all loads (clamped addr, no branches) ----
    float se[NIT], st_[NIT];
    #pragma unroll
    for (int it = 0; it < NIT; ++it) {
        int i = it * 256 + tid;
        int r = i / LW, c = i - r * LW;
        int gy = ty0 - HALO + r;
        int gx = tx0 - HALO + c;
        int cy = min(max(gy, 0), IMG - 1);
        int cx = min(max(gx, 0), IMG - 1);
        int off = cy * IMG + cx;
        if (i < TOTAL) {                 // divergent only at it==12
            se[it]  = pe[off];
            st_[it] = pt[off];
        }
    }

    // ---- stage, phase B: zero-pad select + LDS write ----
    #pragma unroll
    for (int it = 0; it < NIT; ++it) {
        int i = it * 256 + tid;
        if (i < TOTAL) {
            int r = i / LW, c = i - r * LW;
            int gy = ty0 - HALO + r;
            int gx = tx0 - HALO + c;
            bool valid = ((unsigned)gy < (unsigned)IMG) &&
                         ((unsigned)gx < (unsigned)IMG);
            float m = valid ? 1.f : 0.f;
            sS[r * LSTR + c] = (v2f){se[it] * m, st_[it] * m};
        }
    }
    __syncthreads();

    const int wv = tid >> 6;   // wave id 0..3 -> 8-row segment
    const int ln = tid & 63;   // lane -> column
    const int rbase = wv * ROWS_PER_WAVE;
    const v2f* rp = &sS[rbase * LSTR + ln];

    v2f am[ROWS_PER_WAVE];     // (mu1, mu2) accumulators
    v2f aq[ROWS_PER_WAVE];     // (E[e^2], E[t^2]) accumulators
    float ax[ROWS_PER_WAVE];   // E[e*t] accumulator
    #pragma unroll
    for (int o = 0; o < ROWS_PER_WAVE; ++o) {
        am[o] = (v2f){0.f, 0.f}; aq[o] = (v2f){0.f, 0.f}; ax[o] = 0.f;
    }

    #pragma unroll
    for (int rr = 0; rr < STREAM_ROWS; ++rr) {
        // horizontal 11-tap of {(e,t), (e^2,t^2), e*t} for streamed row rr
        v2f hm = {0.f, 0.f};
        v2f hq = {0.f, 0.f};
        float hx = 0.f;
        #pragma unroll
        for (int k = 0; k < WIN; ++k) {
            v2f et = rp[rr * LSTR + k];     // ds_read_b64, imm offset
            float gk = w.g[k];
            v2f g2 = {gk, gk};
            v2f ge = g2 * et;               // v_pk_mul_f32
            hm += ge;                       // v_pk_add_f32
            hq += ge * et;                  // v_pk_fma_f32
            hx += ge.x * et.y;              // scalar v_fmac_f32
        }

        // vertical scatter: streamed row rr feeds output rows rr-10..rr
        #pragma unroll
        for (int k = 0; k < WIN; ++k) {
            int o = rr - k;
            if (o >= 0 && o < ROWS_PER_WAVE) {
                float gk = w.g[k];
                v2f g2 = {gk, gk};
                am[o] += g2 * hm;           // v_pk_fma_f32
                aq[o] += g2 * hq;           // v_pk_fma_f32
                ax[o] += gk * hx;           // v_fmac_f32
            }
        }
    }

    // ---- epilogue: ssim per pixel + L1, then reduce ----
    float ssim_s = 0.f, l1_s = 0.f;
    #pragma unroll
    for (int o = 0; o < ROWS_PER_WAVE; ++o) {
        float mu1 = am[o].x, mu2 = am[o].y;
        float m11 = mu1 * mu1, m22 = mu2 * mu2, m12 = mu1 * mu2;
        float s11 = aq[o].x - m11;
        float s22 = aq[o].y - m22;
        float s12 = ax[o]   - m12;
        float num = (2.f * m12 + C1C) * (2.f * s12 + C2C);
        float den = (m11 + m22 + C1C) * (s11 + s22 + C2C);
        ssim_s += num * __builtin_amdgcn_rcpf(den);

        v2f c = rp[(o + HALO) * LSTR + HALO];  // center {e,t}
        l1_s += fabsf(c.x - c.y);
    }

    // ---- block reduce: wave shfl -> LDS[4] -> thread 0 stores partial ----
    #pragma unroll
    for (int off = 32; off >= 1; off >>= 1) {
        ssim_s += __shfl_xor(ssim_s, off, 64);
        l1_s   += __shfl_xor(l1_s, off, 64);
    }
    if (ln == 0) red[wv] = make_float2(ssim_s, l1_s);
    __syncthreads();
    if (tid == 0) {
        float2 r0 = red[0], r1 = red[1], r2 = red[2], r3 = red[3];
        float2 p = make_float2(r0.x + r1.x + r2.x + r3.x,
                               r0.y + r1.y + r2.y + r3.y);
        int bid = (blockIdx.z * gridDim.y + blockIdx.y) * gridDim.x + blockIdx.x;
        partials[bid] = p;
    }
}

__global__ __launch_bounds__(256) void ssim_reduce(
    const float2* __restrict__ partials, int n, float* __restrict__ out)
{
    __shared__ float2 red[4];
    const int tid = threadIdx.x;
    float ssim_s = 0.f, l1_s = 0.f;
    for (int i = tid; i < n; i += 256) {
        float2 p = partials[i];
        ssim_s += p.x;
        l1_s   += p.y;
    }
    #pragma unroll
    for (int off = 32; off >= 1; off >>= 1) {
        ssim_s += __shfl_xor(ssim_s, off, 64);
        l1_s   += __shfl_xor(l1_s, off, 64);
    }
    if ((tid & 63) == 0) red[tid >> 6] = make_float2(ssim_s, l1_s);
    __syncthreads();
    if (tid == 0) {
        float s = red[0].x + red[1].x + red[2].x + red[3].x;
        float l = red[0].y + red[1].y + red[2].y + red[3].y;
        const float N = 16.f * 3.f * 512.f * 512.f;
        out[0] = 0.15f * (l / N);
        out[1] = 0.85f * 0.5f * (1.f - s / N);
    }
}

extern "C" void kernel_launch(void* const* d_in, const int* in_sizes, int n_in,
                              void* d_out, int out_size, void* d_ws, size_t ws_size,
                              hipStream_t stream)
{
    const float* es = (const float*)d_in[0];
    const float* ta = (const float*)d_in[1];
    float* out = (float*)d_out;
    float2* partials = (float2*)d_ws;

    Wnd w;
    double gd[WIN], sum = 0.0;
    for (int i = 0; i < WIN; ++i) {
        double x = (double)(i - WIN / 2);
        gd[i] = std::exp(-(x * x) / (2.0 * 1.5 * 1.5));
        sum += gd[i];
    }
    for (int i = 0; i < WIN; ++i) w.g[i] = (float)(gd[i] / sum);

    const int nimg = in_sizes[0] / (IMG * IMG);  // 16*3 = 48
    dim3 grid(IMG / TILE_W, IMG / TILE_H, nimg); // 8 x 16 x 48 = 6144 blocks
    const int nblocks = grid.x * grid.y * grid.z;
    ssim_main<<<grid, 256, 0, stream>>>(es, ta, partials, w);
    ssim_reduce<<<1, 256, 0, stream>>>(partials, nblocks, out);
}

// Round 16
// 78.354 us; speedup vs baseline: 2.4942x; 1.3951x over previous
//
#include <hip/hip_runtime.h>
#include <cmath>

// SSIM + L1 image similarity loss, MI355X (gfx950).
// es, ta: fp32 [16,3,512,512]. Output: out[0]=l1_loss, out[1]=ssim_loss.
//
// R16 = R15 (109us: batched staging, packed v2f math, VGPR=128 no-spill)
// with ONE algebraic change: rotate to u=e+t, v=e-t. SSIM needs only
//   m11+m22 = (mu_u^2+mu_v^2)/2     2*m12 = (mu_u^2-mu_v^2)/2
//   s11+s22 = (var_u+var_v)/2       2*s12 = (var_u-var_v)/2
// -> FOUR conv channels (mu_u, mu_v, E[u^2], E[v^2]) instead of five; the
// cross-channel E[e*t] disappears. Per streamed row: horizontal 44->33
// issues, scatter 33->22 (-29% main-loop VALU); accumulators 40->32 regs.
// l1 = |e-t| = |v| read directly. Transform exact in fp32.

typedef float v2f __attribute__((ext_vector_type(2)));

constexpr int TILE_W = 64;
constexpr int TILE_H = 32;
constexpr int HALO = 5;
constexpr int WIN  = 11;
constexpr int ROWS_PER_WAVE = TILE_H / 4;            // 8
constexpr int STREAM_ROWS = ROWS_PER_WAVE + WIN - 1; // 18
constexpr int LH   = TILE_H + 2 * HALO;  // 42 staged rows
constexpr int LW   = TILE_W + 2 * HALO;  // 74 staged cols
constexpr int LSTR = 76;                 // LDS row stride (v2f units)
constexpr int IMG  = 512;
constexpr int TOTAL = LH * LW;           // 3108 staged elements
constexpr int NIT = (TOTAL + 255) / 256; // 13 stage iterations
constexpr float C1C = 0.01f * 0.01f;
constexpr float C2C = 0.03f * 0.03f;

struct Wnd { float g[WIN]; };

__global__ __launch_bounds__(256, 2) void ssim_main(
    const float* __restrict__ es, const float* __restrict__ ta,
    float2* __restrict__ partials, Wnd w)
{
    __shared__ v2f sS[LH * LSTR];
    __shared__ float2 red[4];

    const int tid = threadIdx.x;
    const int tx0 = blockIdx.x * TILE_W;
    const int ty0 = blockIdx.y * TILE_H;
    const int img = blockIdx.z;
    const float* pe = es + (size_t)img * (IMG * IMG);
    const float* pt = ta + (size_t)img * (IMG * IMG);

    // ---- stage, phase A: issue all loads (clamped addr, no branches) ----
    float se[NIT], st_[NIT];
    #pragma unroll
    for (int it = 0; it < NIT; ++it) {
        int i = it * 256 + tid;
        int r = i / LW, c = i - r * LW;
        int gy = ty0 - HALO + r;
        int gx = tx0 - HALO + c;
        int cy = min(max(gy, 0), IMG - 1);
        int cx = min(max(gx, 0), IMG - 1);
        int off = cy * IMG + cx;
        if (i < TOTAL) {                 // divergent only at it==12
            se[it]  = pe[off];
            st_[it] = pt[off];
        }
    }

    // ---- stage, phase B: zero-pad select + (u,v) transform + LDS write ----
    #pragma unroll
    for (int it = 0; it < NIT; ++it) {
        int i = it * 256 + tid;
        if (i < TOTAL) {
            int r = i / LW, c = i - r * LW;
            int gy = ty0 - HALO + r;
            int gx = tx0 - HALO + c;
            bool valid = ((unsigned)gy < (unsigned)IMG) &&
                         ((unsigned)gx < (unsigned)IMG);
            float m = valid ? 1.f : 0.f;
            float e = se[it] * m, t = st_[it] * m;
            sS[r * LSTR + c] = (v2f){e + t, e - t};   // (u, v)
        }
    }
    __syncthreads();

    const int wv = tid >> 6;   // wave id 0..3 -> 8-row segment
    const int ln = tid & 63;   // lane -> column
    const int rbase = wv * ROWS_PER_WAVE;
    const v2f* rp = &sS[rbase * LSTR + ln];

    v2f am[ROWS_PER_WAVE];     // (mu_u, mu_v) accumulators
    v2f aq[ROWS_PER_WAVE];     // (E[u^2], E[v^2]) accumulators
    #pragma unroll
    for (int o = 0; o < ROWS_PER_WAVE; ++o) {
        am[o] = (v2f){0.f, 0.f}; aq[o] = (v2f){0.f, 0.f};
    }

    #pragma unroll
    for (int rr = 0; rr < STREAM_ROWS; ++rr) {
        // horizontal 11-tap of {(u,v), (u^2,v^2)} for streamed row rr
        v2f hm = {0.f, 0.f};
        v2f hq = {0.f, 0.f};
        #pragma unroll
        for (int k = 0; k < WIN; ++k) {
            v2f uv = rp[rr * LSTR + k];     // ds_read_b64, imm offset
            float gk = w.g[k];
            v2f g2 = {gk, gk};
            v2f gu = g2 * uv;               // v_pk_mul_f32
            hm += gu;                       // v_pk_add_f32
            hq += gu * uv;                  // v_pk_fma_f32
        }

        // vertical scatter: streamed row rr feeds output rows rr-10..rr
        #pragma unroll
        for (int k = 0; k < WIN; ++k) {
            int o = rr - k;
            if (o >= 0 && o < ROWS_PER_WAVE) {
                float gk = w.g[k];
                v2f g2 = {gk, gk};
                am[o] += g2 * hm;           // v_pk_fma_f32
                aq[o] += g2 * hq;           // v_pk_fma_f32
            }
        }
    }

    // ---- epilogue: ssim per pixel + L1, then reduce ----
    float ssim_s = 0.f, l1_s = 0.f;
    #pragma unroll
    for (int o = 0; o < ROWS_PER_WAVE; ++o) {
        float mu_u = am[o].x, mu_v = am[o].y;
        float mu_u2 = mu_u * mu_u, mu_v2 = mu_v * mu_v;
        float var_u = aq[o].x - mu_u2;
        float var_v = aq[o].y - mu_v2;
        float m12_2 = (mu_u2 - mu_v2) * 0.5f;   // 2*mu1*mu2
        float msum  = (mu_u2 + mu_v2) * 0.5f;   // mu1^2+mu2^2
        float cov2  = (var_u - var_v) * 0.5f;   // 2*sigma12
        float vsum  = (var_u + var_v) * 0.5f;   // sigma1^2+sigma2^2
        float num = (m12_2 + C1C) * (cov2 + C2C);
        float den = (msum + C1C) * (vsum + C2C);
        ssim_s += num * __builtin_amdgcn_rcpf(den);

        v2f c = rp[(o + HALO) * LSTR + HALO];   // center (u,v)
        l1_s += fabsf(c.y);                     // |e-t| = |v|
    }

    // ---- block reduce: wave shfl -> LDS[4] -> thread 0 stores partial ----
    #pragma unroll
    for (int off = 32; off >= 1; off >>= 1) {
        ssim_s += __shfl_xor(ssim_s, off, 64);
        l1_s   += __shfl_xor(l1_s, off, 64);
    }
    if (ln == 0) red[wv] = make_float2(ssim_s, l1_s);
    __syncthreads();
    if (tid == 0) {
        float2 r0 = red[0], r1 = red[1], r2 = red[2], r3 = red[3];
        float2 p = make_float2(r0.x + r1.x + r2.x + r3.x,
                               r0.y + r1.y + r2.y + r3.y);
        int bid = (blockIdx.z * gridDim.y + blockIdx.y) * gridDim.x + blockIdx.x;
        partials[bid] = p;
    }
}

__global__ __launch_bounds__(256) void ssim_reduce(
    const float2* __restrict__ partials, int n, float* __restrict__ out)
{
    __shared__ float2 red[4];
    const int tid = threadIdx.x;
    float ssim_s = 0.f, l1_s = 0.f;
    for (int i = tid; i < n; i += 256) {
        float2 p = partials[i];
        ssim_s += p.x;
        l1_s   += p.y;
    }
    #pragma unroll
    for (int off = 32; off >= 1; off >>= 1) {
        ssim_s += __shfl_xor(ssim_s, off, 64);
        l1_s   += __shfl_xor(l1_s, off, 64);
    }
    if ((tid & 63) == 0) red[tid >> 6] = make_float2(ssim_s, l1_s);
    __syncthreads();
    if (tid == 0) {
        float s = red[0].x + red[1].x + red[2].x + red[3].x;
        float l = red[0].y + red[1].y + red[2].y + red[3].y;
        const float N = 16.f * 3.f * 512.f * 512.f;
        out[0] = 0.15f * (l / N);
        out[1] = 0.85f * 0.5f * (1.f - s / N);
    }
}

extern "C" void kernel_launch(void* const* d_in, const int* in_sizes, int n_in,
                              void* d_out, int out_size, void* d_ws, size_t ws_size,
                              hipStream_t stream)
{
    const float* es = (const float*)d_in[0];
    const float* ta = (const float*)d_in[1];
    float* out = (float*)d_out;
    float2* partials = (float2*)d_ws;

    Wnd w;
    double gd[WIN], sum = 0.0;
    for (int i = 0; i < WIN; ++i) {
        double x = (double)(i - WIN / 2);
        gd[i] = std::exp(-(x * x) / (2.0 * 1.5 * 1.5));
        sum += gd[i];
    }
    for (int i = 0; i < WIN; ++i) w.g[i] = (float)(gd[i] / sum);

    const int nimg = in_sizes[0] / (IMG * IMG);  // 16*3 = 48
    dim3 grid(IMG / TILE_W, IMG / TILE_H, nimg); // 8 x 16 x 48 = 6144 blocks
    const int nblocks = grid.x * grid.y * grid.z;
    ssim_main<<<grid, 256, 0, stream>>>(es, ta, partials, w);
    ssim_reduce<<<1, 256, 0, stream>>>(partials, nblocks, out);
}